// Round 7
// baseline (358.138 us; speedup 1.0000x reference)
//
#include <hip/hip_runtime.h>

#define Bn 256
#define Tn 512
#define Cn 256
#define Kn 8

typedef __attribute__((ext_vector_type(4))) float f32x4;

// v8: attack the latency-bound regime (all pipes <17% busy in v1..v7) with
// the one untested lever: 8 waves/SIMD.
//
// Evidence: 2 w/S = 80us (v4/v5), 4 w/S = ~70us (v1/v7, identical core to
// v5), spill @64-reg with a HEAVY core = 88-137us (v2/v6). v7 proved spill
// elimination alone is neutral -> latency, not scratch, binds at 4 w/S.
//
// Geometry: grid 512 (one t/block), 1024 thr = 16 waves, single 64 KiB fp8
// tile (~68 KB LDS) -> 2 blocks/CU -> 32 waves/CU = 8 waves/SIMD.
// __launch_bounds__(1024, 8) caps the allocator at 64 VGPR; the core is
// sized to fit: wave owns 16 rows -> acc[2] (8 regs), per-kp transient
// 1 A + 2 B frags (12), epilogue state 16, addressing ~12 -> peak ~50 < 64.
// (v2 failed this budget with a ~160-reg core; that was demand, not budget.)
//
// LDS tile layout (unchanged from v1): fp8 e4m3, paired-K swizzle — logical
// 8-byte half-unit b=kk*4+q (k-bytes [kk*32+q*8, +8)) stored at physical
// 16B unit u=(q*4+kp)^(row&7), half (kk&1): one ds_read_b128 feeds MFMAs
// kk=2kp, 2kp+1.
__global__ __launch_bounds__(1024, 8)
void tcon_k(const float* __restrict__ emb,
            const int* __restrict__ phon,
            const float* __restrict__ wts,
            float* __restrict__ out) {
    __shared__ __align__(16) unsigned char Esh[Bn * Bn];   // 64 KiB fp8
    __shared__ float invn[Bn];
    __shared__ int   pcls[Bn];
    __shared__ float num_s[Bn], den_s[Bn];
    __shared__ float csum[Kn];
    __shared__ int   ccnt[Kn];

    const int t    = blockIdx.x;
    const int tid  = threadIdx.x;
    const int lane = tid & 63;
    const int wave = tid >> 6;        // 0..15
    const int i0   = wave * 16;       // rows [i0, i0+16)
    const int g0   = wave >> 1;       // col-group holding this wave's diagonal

    const int q   = lane >> 4;
    const int l15 = lane & 15;
    const int e3  = l15 & 7;          // == row&7 for all our fragment rows

    if (tid < Kn) { csum[tid] = 0.0f; ccnt[tid] = 0; }
    if (tid < Bn) pcls[tid] = phon[tid * Tn + t];

    // ---- Phase 1: stream fp32 -> fp8 e4m3 into paired-K swizzled LDS ----
    // 1024 threads x 8 units x 32 B = 256 KB fp32 -> 64 KB fp8.
    #pragma unroll 4
    for (int it = 0; it < 8; ++it) {
        const int f   = tid + it * 1024;
        const int row = f >> 5;
        const int b   = f & 31;                 // logical 8B half-unit
        const float4* p = (const float4*)(emb + ((size_t)row * Tn + t) * Cn);
        const float4 v0 = p[2 * b];
        const float4 v1 = p[2 * b + 1];
        int lo = __builtin_amdgcn_cvt_pk_fp8_f32(v0.x, v0.y, 0, false);
        lo     = __builtin_amdgcn_cvt_pk_fp8_f32(v0.z, v0.w, lo, true);
        int hi = __builtin_amdgcn_cvt_pk_fp8_f32(v1.x, v1.y, 0, false);
        hi     = __builtin_amdgcn_cvt_pk_fp8_f32(v1.z, v1.w, hi, true);
        const int qq = b & 3, kk = b >> 2, kp = kk >> 1;
        const int ad = row * 256 + ((((qq << 2) + kp) ^ (row & 7)) << 4)
                     + ((kk & 1) << 3);
        int2 pk; pk.x = lo; pk.y = hi;
        *(int2*)&Esh[ad] = pk;
    }
    __syncthreads();

    f32x4 acc[2];

// 16-row x 32-col block vs col-group (JB = col base). Transient in-flight set
// per kp: 1 A + 2 B ulonglong2 = 12 VGPRs; acc[2] static-indexed.
#define COMPUTE_G(JB) do {                                                   \
    acc[0] = (f32x4){0.f, 0.f, 0.f, 0.f};                                    \
    acc[1] = (f32x4){0.f, 0.f, 0.f, 0.f};                                    \
    _Pragma("unroll") for (int _kp = 0; _kp < 4; ++_kp) {                    \
        const int _sw = (((q << 2) + _kp) ^ e3) << 4;                        \
        const ulonglong2 _a = *(const ulonglong2*)&Esh[(i0 + l15) * 256 + _sw]; \
        ulonglong2 _b[2];                                                    \
        _Pragma("unroll") for (int _n = 0; _n < 2; ++_n)                     \
            _b[_n] = *(const ulonglong2*)&Esh[((JB) + _n * 16 + l15) * 256 + _sw]; \
        _Pragma("unroll") for (int _n = 0; _n < 2; ++_n) {                   \
            acc[_n] = __builtin_amdgcn_mfma_f32_16x16x32_fp8_fp8(            \
                (long)_a.x, (long)_b[_n].x, acc[_n], 0, 0, 0);               \
            acc[_n] = __builtin_amdgcn_mfma_f32_16x16x32_fp8_fp8(            \
                (long)_a.y, (long)_b[_n].y, acc[_n], 0, 0, 0);               \
        }                                                                    \
    }                                                                        \
} while (0)

// acc[n][r] holds S(row = i0 + q*4 + r, col = JB + n*16 + l15).
#define EPILOGUE(JB) do {                                                    \
    _Pragma("unroll") for (int _n = 0; _n < 2; ++_n) {                       \
        const int _j  = (JB) + _n * 16 + l15;                                \
        const int _pj = pcls[_j];                                            \
        const float _ij = invn[_j];                                          \
        _Pragma("unroll") for (int _r = 0; _r < 4; ++_r) {                   \
            const int _ir = i0 + q * 4 + _r;                                 \
            const float _ex = __expf(acc[_n][_r] * inv_i[_r] * _ij);         \
            const bool _nd = (_ir != _j);                                    \
            den_p[_r] += _nd ? _ex : 0.0f;                                   \
            num_p[_r] += (_nd && (_pj == pi[_r])) ? _ex : 0.0f;              \
        }                                                                    \
    }                                                                        \
} while (0)

    // ---- diagonal col-group first; publish this wave's 16 norms ----
    // Diagonal of rows [i0,i0+16) sits at n = wave&1, l15 == q*4+r.
    COMPUTE_G(g0 * 32);
    if ((wave & 1) == 0) {
        #pragma unroll
        for (int r = 0; r < 4; ++r)
            if (l15 == q * 4 + r)
                invn[i0 + l15] = rsqrtf(fmaxf(acc[0][r], 1e-24f));
    } else {
        #pragma unroll
        for (int r = 0; r < 4; ++r)
            if (l15 == q * 4 + r)
                invn[i0 + l15] = rsqrtf(fmaxf(acc[1][r], 1e-24f));
    }
    __syncthreads();               // all norms published

    float num_p[4], den_p[4], inv_i[4];
    int   pi[4];
    #pragma unroll
    for (int e = 0; e < 4; ++e) {
        const int irow = i0 + q * 4 + e;
        num_p[e] = 0.0f; den_p[e] = 0.0f;
        pi[e]    = pcls[irow];
        inv_i[e] = invn[irow];
    }

    EPILOGUE(g0 * 32);             // consume held diagonal acc
    for (int k = 1; k < 8; ++k) {  // remaining col-groups (wave-uniform)
        const int jb = (g0 ^ k) * 32;
        COMPUTE_G(jb);
        EPILOGUE(jb);
    }

    // Reduce across the 16 l15 lanes; each lane-quad (q) owns 4 rows.
    #pragma unroll
    for (int e = 0; e < 4; ++e) {
        float n = num_p[e], d = den_p[e];
        #pragma unroll
        for (int m = 1; m <= 8; m <<= 1) {
            n += __shfl_xor(n, m, 64);
            d += __shfl_xor(d, m, 64);
        }
        if (l15 == e) {
            num_s[i0 + q * 4 + e] = n;
            den_s[i0 + q * 4 + e] = d;
        }
    }
    __syncthreads();

    // ---- Phase 3: per-sample loss, class means, weighted mean ----
    if (tid < Bn) {
        const float ps = __logf(den_s[tid] + 1e-6f) - __logf(num_s[tid]);
        atomicAdd(&csum[pcls[tid]], ps);
        atomicAdd(&ccnt[pcls[tid]], 1);
    }
    __syncthreads();

    if (tid == 0) {
        float accv = 0.0f; int np = 0;
        #pragma unroll
        for (int k = 0; k < Kn; ++k)
            if (ccnt[k] > 0) { accv += (csum[k] / (float)ccnt[k]) * wts[k]; ++np; }
        atomicAdd(out, (accv / (float)np) * (1.0f / (float)Tn));
    }
#undef COMPUTE_G
#undef EPILOGUE
}

extern "C" void kernel_launch(void* const* d_in, const int* in_sizes, int n_in,
                              void* d_out, int out_size, void* d_ws, size_t ws_size,
                              hipStream_t stream) {
    const float* emb  = (const float*)d_in[0];
    const int*   phon = (const int*)d_in[1];
    const float* wts  = (const float*)d_in[2];
    float*       out  = (float*)d_out;

    hipMemsetAsync(out, 0, sizeof(float), stream);
    tcon_k<<<Tn, 1024, 0, stream>>>(emb, phon, wts, out);
}

// Round 8
// 212.928 us; speedup vs baseline: 1.6820x; 1.6820x over previous
//
#include <hip/hip_runtime.h>

#define Bn 256
#define Tn 512
#define Cn 256
#define Kn 8

typedef __attribute__((ext_vector_type(4))) float f32x4;
typedef __attribute__((address_space(1))) const unsigned char g_u8;
typedef __attribute__((address_space(3))) unsigned char l_u8;

// v9: split the op into two kernels.
//
// Evidence trail: v1/v7 (4 w/S) = ~52us kernel; 2 w/S = 80; 8 w/S = spill
// disaster (v8: VGPR=32, 340 MB scratch). At 4 w/S the kernel is ~half
// staging (strided fp32 read + cvt VALU + diagonal-norm pass, repeated per t)
// and ~half latency-bound compute; no compute-core rearrangement moved it
// (v7 null result). So hoist ALL t-invariant staging work into a one-shot
// streaming prep kernel:
//
//  tcon_p: one wave per (b,t) row. Coalesced 1KB fp32 read, exact norm via
//    shfl reduce, normalize, fp8-e4m3 quantize, scatter into the PHYSICAL
//    paired-K swizzled layout, tiled 64KB per t in workspace. The main
//    kernel's LDS image is then a verbatim copy of global memory.
//  tcon_m: v7 shell (grid 512, 512 thr, 2 blk/CU, 4 w/S) but staging is a
//    linear 64KB global_load_lds DMA (no VGPR round-trip, no cvt), and
//    pre-normalized rows remove invn / diagonal-first order / one barrier /
//    2 VALU per element. Compute core = v7's proven acc[2][2] half-strips.
//
// Physical layout per t (matches COMPUTE_HALF's reads, same as v1..v7):
// row r, k-byte k: kk=k>>5, q=(k&31)>>3, o=k&7, kp=kk>>1, h=kk&1,
// unit u=((q<<2)+kp)^(r&7); byte addr = r*256 + u*16 + h*8 + o.
// One ds_read_b128 at unit u feeds MFMAs kk=2kp (low 8B) and 2kp+1 (high 8B).
//
// Fallback: if ws_size < 33.5 MB, launch tcon_f (verbatim v7, known ~52us).

// ---------------- Kernel P: normalize + quantize + pack ----------------
__global__ __launch_bounds__(512, 4)
void tcon_p(const float* __restrict__ emb, unsigned char* __restrict__ q8) {
    const int tid  = threadIdx.x;
    const int lane = tid & 63;
    const int wave = tid >> 6;                 // 0..7
    const int R    = blockIdx.x * 8 + wave;    // linear (b,t) row, = b*Tn + t
    const int b    = R >> 9;                   // Tn = 512
    const int t    = R & (Tn - 1);

    // one float4 per lane: 64 lanes x 4 floats = 256 = Cn, contiguous 1KB
    const float4 v = ((const float4*)(emb + (size_t)R * Cn))[lane];
    float n2 = v.x * v.x + v.y * v.y + v.z * v.z + v.w * v.w;
    #pragma unroll
    for (int m = 1; m <= 32; m <<= 1) n2 += __shfl_xor(n2, m, 64);
    const float inv = rsqrtf(fmaxf(n2, 1e-24f));   // == 1/max(||x||,1e-12)

    int pk = __builtin_amdgcn_cvt_pk_fp8_f32(v.x * inv, v.y * inv, 0, false);
    pk     = __builtin_amdgcn_cvt_pk_fp8_f32(v.z * inv, v.w * inv, pk, true);

    // lane owns k = 4*lane .. 4*lane+3 (same 8-byte q-slot)
    const int q  = (lane >> 1) & 3;
    const int kp = lane >> 4;
    const int h  = (lane >> 3) & 1;
    const int u  = ((q << 2) + kp) ^ (b & 7);
    const size_t ad = (size_t)t * (Bn * Cn) + b * 256 + u * 16 + h * 8
                    + (lane & 1) * 4;
    *(int*)&q8[ad] = pk;
}

// ---------------- Kernel M: per-t contrastive loss ----------------
__global__ __launch_bounds__(512, 4)
void tcon_m(const unsigned char* __restrict__ q8,
            const int* __restrict__ phon,
            const float* __restrict__ wts,
            float* __restrict__ out) {
    __shared__ __align__(16) unsigned char Esh[Bn * Cn];   // 64 KiB fp8
    __shared__ int   pcls[Bn];
    __shared__ float num_s[Bn], den_s[Bn];
    __shared__ float csum[Kn];
    __shared__ int   ccnt[Kn];

    const int t    = blockIdx.x;
    const int tid  = threadIdx.x;
    const int lane = tid & 63;
    const int wave = tid >> 6;        // 0..7
    const int i0   = wave * 32;       // rows [i0, i0+32)

    const int q   = lane >> 4;
    const int l15 = lane & 15;
    const int e3  = l15 & 7;          // == row&7 for all our fragment rows

    if (tid < Kn) { csum[tid] = 0.0f; ccnt[tid] = 0; }
    if (tid < Bn) pcls[tid] = phon[tid * Tn + t];

    // ---- stage: linear 64 KB DMA, global image == LDS image ----
    {
        const unsigned char* gt = q8 + (size_t)t * (Bn * Cn);
        #pragma unroll
        for (int i = 0; i < 8; ++i) {
            __builtin_amdgcn_global_load_lds(
                (g_u8*)(gt + wave * 8192 + i * 1024 + lane * 16),
                (l_u8*)&Esh[wave * 8192 + i * 1024],
                16, 0, 0);
        }
    }
    __syncthreads();   // drains vmcnt (DMA) + covers pcls/csum writes

    f32x4 acc[2][2];

// 32-col half-strip; A and B read transiently (8+8 ds_read_b128 in flight).
#define COMPUTE_HALF(JB) do {                                                \
    _Pragma("unroll") for (int _m = 0; _m < 2; ++_m)                         \
    _Pragma("unroll") for (int _n = 0; _n < 2; ++_n)                         \
        acc[_m][_n] = (f32x4){0.f, 0.f, 0.f, 0.f};                           \
    _Pragma("unroll") for (int _kp = 0; _kp < 4; ++_kp) {                    \
        const int _sw = (((q << 2) + _kp) ^ e3) << 4;                        \
        ulonglong2 _a[2], _b[2];                                             \
        _Pragma("unroll") for (int _m = 0; _m < 2; ++_m)                     \
            _a[_m] = *(const ulonglong2*)&Esh[(i0 + _m * 16 + l15) * 256 + _sw]; \
        _Pragma("unroll") for (int _n = 0; _n < 2; ++_n)                     \
            _b[_n] = *(const ulonglong2*)&Esh[((JB) + _n * 16 + l15) * 256 + _sw]; \
        _Pragma("unroll") for (int _m = 0; _m < 2; ++_m)                     \
        _Pragma("unroll") for (int _n = 0; _n < 2; ++_n) {                   \
            acc[_m][_n] = __builtin_amdgcn_mfma_f32_16x16x32_fp8_fp8(        \
                (long)_a[_m].x, (long)_b[_n].x, acc[_m][_n], 0, 0, 0);       \
            acc[_m][_n] = __builtin_amdgcn_mfma_f32_16x16x32_fp8_fp8(        \
                (long)_a[_m].y, (long)_b[_n].y, acc[_m][_n], 0, 0, 0);       \
        }                                                                    \
    }                                                                        \
} while (0)

// Pre-normalized rows: S = acc directly, no inv scaling.
#define EPILOGUE(JB) do {                                                    \
    _Pragma("unroll") for (int _n = 0; _n < 2; ++_n) {                       \
        const int _j  = (JB) + _n * 16 + l15;                                \
        const int _pj = pcls[_j];                                            \
        _Pragma("unroll") for (int _m = 0; _m < 2; ++_m)                     \
        _Pragma("unroll") for (int _r = 0; _r < 4; ++_r) {                   \
            const int _e = _m * 4 + _r;                                      \
            const int _ir = i0 + _m * 16 + q * 4 + _r;                       \
            const float _ex = __expf(acc[_m][_n][_r]);                       \
            const bool _nd = (_ir != _j);                                    \
            den_p[_e] += _nd ? _ex : 0.0f;                                   \
            num_p[_e] += (_nd && (_pj == pi[_e])) ? _ex : 0.0f;              \
        }                                                                    \
    }                                                                        \
} while (0)

    float num_p[8], den_p[8];
    int   pi[8];
    #pragma unroll
    for (int e = 0; e < 8; ++e) {
        const int irow = i0 + (e >> 2) * 16 + q * 4 + (e & 3);
        num_p[e] = 0.0f; den_p[e] = 0.0f;
        pi[e]    = pcls[irow];
    }

    for (int k = 0; k < 8; ++k) {   // all 8 half-strips, wave-uniform order
        const int jb = (wave ^ k) * 32;
        COMPUTE_HALF(jb);
        EPILOGUE(jb);
    }

    // Reduce across the 16 l15 lanes of each quad; each row owned by 1 wave.
    #pragma unroll
    for (int e = 0; e < 8; ++e) {
        float n = num_p[e], d = den_p[e];
        #pragma unroll
        for (int m = 1; m <= 8; m <<= 1) {
            n += __shfl_xor(n, m, 64);
            d += __shfl_xor(d, m, 64);
        }
        if (l15 == e) {
            const int irow = i0 + (e >> 2) * 16 + q * 4 + (e & 3);
            num_s[irow] = n;
            den_s[irow] = d;
        }
    }
    __syncthreads();

    // ---- per-sample loss, class means, weighted mean ----
    if (tid < Bn) {
        const float ps = __logf(den_s[tid] + 1e-6f) - __logf(num_s[tid]);
        atomicAdd(&csum[pcls[tid]], ps);
        atomicAdd(&ccnt[pcls[tid]], 1);
    }
    __syncthreads();

    if (tid == 0) {
        float accv = 0.0f; int np = 0;
        #pragma unroll
        for (int k = 0; k < Kn; ++k)
            if (ccnt[k] > 0) { accv += (csum[k] / (float)ccnt[k]) * wts[k]; ++np; }
        atomicAdd(out, (accv / (float)np) * (1.0f / (float)Tn));
    }
#undef COMPUTE_HALF
#undef EPILOGUE
}

// ---------------- Kernel F: verbatim v7 fallback (no workspace) ----------
__global__ __launch_bounds__(512, 4)
void tcon_f(const float* __restrict__ emb,
            const int* __restrict__ phon,
            const float* __restrict__ wts,
            float* __restrict__ out) {
    __shared__ __align__(16) unsigned char Esh[Bn * Cn];
    __shared__ float invn[Bn];
    __shared__ int   pcls[Bn];
    __shared__ float num_s[Bn], den_s[Bn];
    __shared__ float csum[Kn];
    __shared__ int   ccnt[Kn];

    const int t    = blockIdx.x;
    const int tid  = threadIdx.x;
    const int lane = tid & 63;
    const int wave = tid >> 6;
    const int i0   = wave * 32;

    const int q   = lane >> 4;
    const int l15 = lane & 15;
    const int e3  = l15 & 7;

    if (tid < Kn) { csum[tid] = 0.0f; ccnt[tid] = 0; }
    if (tid < Bn) pcls[tid] = phon[tid * Tn + t];

    #pragma unroll 4
    for (int it = 0; it < 16; ++it) {
        const int f   = tid + it * 512;
        const int row = f >> 5;
        const int b   = f & 31;
        const float4* p = (const float4*)(emb + ((size_t)row * Tn + t) * Cn);
        const float4 v0 = p[2 * b];
        const float4 v1 = p[2 * b + 1];
        int lo = __builtin_amdgcn_cvt_pk_fp8_f32(v0.x, v0.y, 0, false);
        lo     = __builtin_amdgcn_cvt_pk_fp8_f32(v0.z, v0.w, lo, true);
        int hi = __builtin_amdgcn_cvt_pk_fp8_f32(v1.x, v1.y, 0, false);
        hi     = __builtin_amdgcn_cvt_pk_fp8_f32(v1.z, v1.w, hi, true);
        const int qq = b & 3, kk = b >> 2, kp = kk >> 1;
        const int ad = row * 256 + ((((qq << 2) + kp) ^ (row & 7)) << 4)
                     + ((kk & 1) << 3);
        int2 pk; pk.x = lo; pk.y = hi;
        *(int2*)&Esh[ad] = pk;
    }
    __syncthreads();

    f32x4 acc[2][2];

#define COMPUTE_HALF(JB) do {                                                \
    _Pragma("unroll") for (int _m = 0; _m < 2; ++_m)                         \
    _Pragma("unroll") for (int _n = 0; _n < 2; ++_n)                         \
        acc[_m][_n] = (f32x4){0.f, 0.f, 0.f, 0.f};                           \
    _Pragma("unroll") for (int _kp = 0; _kp < 4; ++_kp) {                    \
        const int _sw = (((q << 2) + _kp) ^ e3) << 4;                        \
        ulonglong2 _a[2], _b[2];                                             \
        _Pragma("unroll") for (int _m = 0; _m < 2; ++_m)                     \
            _a[_m] = *(const ulonglong2*)&Esh[(i0 + _m * 16 + l15) * 256 + _sw]; \
        _Pragma("unroll") for (int _n = 0; _n < 2; ++_n)                     \
            _b[_n] = *(const ulonglong2*)&Esh[((JB) + _n * 16 + l15) * 256 + _sw]; \
        _Pragma("unroll") for (int _m = 0; _m < 2; ++_m)                     \
        _Pragma("unroll") for (int _n = 0; _n < 2; ++_n) {                   \
            acc[_m][_n] = __builtin_amdgcn_mfma_f32_16x16x32_fp8_fp8(        \
                (long)_a[_m].x, (long)_b[_n].x, acc[_m][_n], 0, 0, 0);       \
            acc[_m][_n] = __builtin_amdgcn_mfma_f32_16x16x32_fp8_fp8(        \
                (long)_a[_m].y, (long)_b[_n].y, acc[_m][_n], 0, 0, 0);       \
        }                                                                    \
    }                                                                        \
} while (0)

#define EPILOGUE(JB) do {                                                    \
    _Pragma("unroll") for (int _n = 0; _n < 2; ++_n) {                       \
        const int _j  = (JB) + _n * 16 + l15;                                \
        const int _pj = pcls[_j];                                            \
        const float _ij = invn[_j];                                          \
        _Pragma("unroll") for (int _m = 0; _m < 2; ++_m)                     \
        _Pragma("unroll") for (int _r = 0; _r < 4; ++_r) {                   \
            const int _e = _m * 4 + _r;                                      \
            const int _ir = i0 + _m * 16 + q * 4 + _r;                       \
            const float _ex = __expf(acc[_m][_n][_r] * inv_i[_e] * _ij);     \
            const bool _nd = (_ir != _j);                                    \
            den_p[_e] += _nd ? _ex : 0.0f;                                   \
            num_p[_e] += (_nd && (_pj == pi[_e])) ? _ex : 0.0f;              \
        }                                                                    \
    }                                                                        \
} while (0)

    COMPUTE_HALF(i0);
    #pragma unroll
    for (int r = 0; r < 4; ++r)
        if (l15 == q * 4 + r) {
            invn[i0 + l15]      = rsqrtf(fmaxf(acc[0][0][r], 1e-24f));
            invn[i0 + 16 + l15] = rsqrtf(fmaxf(acc[1][1][r], 1e-24f));
        }
    __syncthreads();

    float num_p[8], den_p[8], inv_i[8];
    int   pi[8];
    #pragma unroll
    for (int e = 0; e < 8; ++e) {
        const int irow = i0 + (e >> 2) * 16 + q * 4 + (e & 3);
        num_p[e] = 0.0f; den_p[e] = 0.0f;
        pi[e]    = pcls[irow];
        inv_i[e] = invn[irow];
    }

    EPILOGUE(i0);
    for (int k = 1; k < 8; ++k) {
        const int jb = (wave ^ k) * 32;
        COMPUTE_HALF(jb);
        EPILOGUE(jb);
    }

    #pragma unroll
    for (int e = 0; e < 8; ++e) {
        float n = num_p[e], d = den_p[e];
        #pragma unroll
        for (int m = 1; m <= 8; m <<= 1) {
            n += __shfl_xor(n, m, 64);
            d += __shfl_xor(d, m, 64);
        }
        if (l15 == e) {
            const int irow = i0 + (e >> 2) * 16 + q * 4 + (e & 3);
            num_s[irow] = n;
            den_s[irow] = d;
        }
    }
    __syncthreads();

    if (tid < Bn) {
        const float ps = __logf(den_s[tid] + 1e-6f) - __logf(num_s[tid]);
        atomicAdd(&csum[pcls[tid]], ps);
        atomicAdd(&ccnt[pcls[tid]], 1);
    }
    __syncthreads();

    if (tid == 0) {
        float accv = 0.0f; int np = 0;
        #pragma unroll
        for (int k = 0; k < Kn; ++k)
            if (ccnt[k] > 0) { accv += (csum[k] / (float)ccnt[k]) * wts[k]; ++np; }
        atomicAdd(out, (accv / (float)np) * (1.0f / (float)Tn));
    }
#undef COMPUTE_HALF
#undef EPILOGUE
}

extern "C" void kernel_launch(void* const* d_in, const int* in_sizes, int n_in,
                              void* d_out, int out_size, void* d_ws, size_t ws_size,
                              hipStream_t stream) {
    const float* emb  = (const float*)d_in[0];
    const int*   phon = (const int*)d_in[1];
    const float* wts  = (const float*)d_in[2];
    float*       out  = (float*)d_out;

    hipMemsetAsync(out, 0, sizeof(float), stream);

    const size_t need = (size_t)Tn * Bn * Cn;   // 33,554,432 B fp8 tiles
    if (d_ws != nullptr && ws_size >= need) {
        unsigned char* q8 = (unsigned char*)d_ws;
        tcon_p<<<(Bn * Tn) / 8, 512, 0, stream>>>(emb, q8);
        tcon_m<<<Tn, 512, 0, stream>>>(q8, phon, wts, out);
    } else {
        tcon_f<<<Tn, 512, 0, stream>>>(emb, phon, wts, out);
    }
}